// Round 12
// baseline (182.553 us; speedup 1.0000x reference)
//
#include <hip/hip_runtime.h>
#include <hip/hip_bf16.h>
#include <math.h>
#include <stdint.h>

#define N_ATOMS 512
#define NF 64
#define NB 8
#define NBINS 64
#define NSEG 511   // segment nodes 0..510; valid pairs i<j, j>=i+2
#define NT 4096    // m(wr) lookup-table grid points over wr in [-1,1]

__device__ __forceinline__ float dot3(float ax, float ay, float az,
                                      float bx, float by, float bz) {
    return fmaf(ax, bx, fmaf(ay, by, az * bz));
}

__device__ __forceinline__ uint16_t bf16_bits(float f) {
    union { __hip_bfloat16 h; uint16_t u; } cv;
    cv.h = __float2bfloat16(f);
    return cv.u;
}

// writhe scalar for edge (i,j), i<j — verified (R2..R11 absmax 0.0625)
__device__ __forceinline__ float compute_wr(const float* __restrict__ pb, int i, int j) {
    float p0x = pb[3*i+0], p0y = pb[3*i+1], p0z = pb[3*i+2];
    float p1x = pb[3*i+3], p1y = pb[3*i+4], p1z = pb[3*i+5];
    float p2x = pb[3*j+0], p2y = pb[3*j+1], p2z = pb[3*j+2];
    float p3x = pb[3*j+3], p3y = pb[3*j+4], p3z = pb[3*j+5];

    float d0x = p2x-p0x, d0y = p2y-p0y, d0z = p2z-p0z;
    float d1x = p3x-p0x, d1y = p3y-p0y, d1z = p3z-p0z;
    float d2x = p2x-p1x, d2y = p2y-p1y, d2z = p2z-p1z;
    float d3x = p3x-p1x, d3y = p3y-p1y, d3z = p3z-p1z;
    {
        float n0 = rsqrtf(dot3(d0x,d0y,d0z,d0x,d0y,d0z)); d0x*=n0; d0y*=n0; d0z*=n0;
        float n1 = rsqrtf(dot3(d1x,d1y,d1z,d1x,d1y,d1z)); d1x*=n1; d1y*=n1; d1z*=n1;
        float n2 = rsqrtf(dot3(d2x,d2y,d2z,d2x,d2y,d2z)); d2x*=n2; d2y*=n2; d2z*=n2;
        float n3 = rsqrtf(dot3(d3x,d3y,d3z,d3x,d3y,d3z)); d3x*=n3; d3y*=n3; d3z*=n3;
    }
    float c0x = d0y*d1z - d0z*d1y, c0y = d0z*d1x - d0x*d1z, c0z = d0x*d1y - d0y*d1x;
    float c1x = d1y*d3z - d1z*d3y, c1y = d1z*d3x - d1x*d3z, c1z = d1x*d3y - d1y*d3x;
    float c3x = d2y*d0z - d2z*d0y, c3y = d2z*d0x - d2x*d0z, c3z = d2x*d0y - d2y*d0x;
    {
        float n0 = rsqrtf(dot3(c0x,c0y,c0z,c0x,c0y,c0z)); c0x*=n0; c0y*=n0; c0z*=n0;
        float n1 = rsqrtf(dot3(c1x,c1y,c1z,c1x,c1y,c1z)); c1x*=n1; c1y*=n1; c1z*=n1;
        float n3 = rsqrtf(dot3(c3x,c3y,c3z,c3x,c3y,c3z)); c3x*=n3; c3y*=n3; c3z*=n3;
    }
    float t0 = fminf(fmaxf(dot3(c0x,c0y,c0z, c1x,c1y,c1z), -1.f), 1.f);
    float t1 = fminf(fmaxf(dot3(c1x,c1y,c1z, c3x,c3y,c3z), -1.f), 1.f);
    float t3 = fminf(fmaxf(dot3(c3x,c3y,c3z, c0x,c0y,c0z), -1.f), 1.f);
    float omega = asinf(t0) + asinf(t1) + asinf(t3) + 1.5707963267948966f;
    float ex = p3x-p2x, ey = p3y-p2y, ez = p3z-p2z;
    float fx = p1x-p0x, fy = p1y-p0y, fz = p1z-p0z;
    float gx = ey*fz - ez*fy, gy = ez*fx - ex*fz, gz = ex*fy - ey*fx;
    float sgd = dot3(gx,gy,gz, d0x,d0y,d0z);
    float sgn = (sgd > 0.f) ? 1.f : ((sgd < 0.f) ? -1.f : 0.f);
    return omega * sgn * 0.15915494309189535f;
}

// ---------------- kernel A: m(wr) table, packed pairs directly ------------------
// One wave per grid point g: computes m(g) AND m(g+1) (redundant-but-cheap; float
// sequence identical to the wave that owns g+1 -> bit-identical table), writes
// {bf16 m_g, bf16 m_{g+1}} in one store. Eliminates the pack kernel. ILP-4 sums.
__launch_bounds__(256)
__global__ void build_tab4(const float* __restrict__ W1, const float* __restrict__ b1,
                           const float* __restrict__ W2, const float* __restrict__ b2,
                           uint32_t* __restrict__ tabp) {
    __shared__ float w1s[4096];
    __shared__ float w2s[4096];
    __shared__ float lha[4][64];
    __shared__ float lhb[4][64];

    const int t = threadIdx.x;
    #pragma unroll
    for (int it = 0; it < 16; ++it) {
        w1s[it * 256 + t] = W1[it * 256 + t];
        w2s[it * 256 + t] = W2[it * 256 + t];
    }
    __syncthreads();

    const int widx = t >> 6;
    const int lane = t & 63;
    const int g = blockIdx.x * 4 + widx;

    float wra = -1.0f + (2.0f / (float)(NT - 1)) * (float)g;        // same expr R6..R11
    float wrb = -1.0f + (2.0f / (float)(NT - 1)) * (float)(g + 1);  // (g=NT-1: unused .y)
    float tta = (wra + 1.0f) * 31.5f;
    float ttb = (wrb + 1.0f) * 31.5f;

    float a0=0.f,a1=0.f,a2=0.f,a3=0.f, e0=0.f,e1=0.f,e2=0.f,e3=0.f;
    #pragma unroll
    for (int k = 0; k < NBINS; k += 4) {
        #pragma unroll
        for (int q = 0; q < 4; ++q) {
            float da = tta - (float)(k + q);
            float db = ttb - (float)(k + q);
            float ra = __expf(-da * da) * 0.8928571428571429f;
            float rb = __expf(-db * db) * 0.8928571428571429f;
            float wv = w1s[(k + q) * NF + lane];
            if (q == 0) { a0 = fmaf(ra, wv, a0); e0 = fmaf(rb, wv, e0); }
            if (q == 1) { a1 = fmaf(ra, wv, a1); e1 = fmaf(rb, wv, e1); }
            if (q == 2) { a2 = fmaf(ra, wv, a2); e2 = fmaf(rb, wv, e2); }
            if (q == 3) { a3 = fmaf(ra, wv, a3); e3 = fmaf(rb, wv, e3); }
        }
    }
    float ha = ((a0 + a1) + (a2 + a3)) + b1[lane];
    float hb = ((e0 + e1) + (e2 + e3)) + b1[lane];
    ha = fmaxf(ha, 0.01f * ha);
    hb = fmaxf(hb, 0.01f * hb);
    lha[widx][lane] = ha;
    lhb[widx][lane] = hb;
    __syncthreads();

    float m0=0.f,m1=0.f,m2=0.f,m3=0.f, n0=0.f,n1=0.f,n2=0.f,n3=0.f;
    #pragma unroll
    for (int k = 0; k < NF; k += 4) {
        m0 = fmaf(lha[widx][k + 0], w2s[(k + 0) * NF + lane], m0);
        m1 = fmaf(lha[widx][k + 1], w2s[(k + 1) * NF + lane], m1);
        m2 = fmaf(lha[widx][k + 2], w2s[(k + 2) * NF + lane], m2);
        m3 = fmaf(lha[widx][k + 3], w2s[(k + 3) * NF + lane], m3);
        n0 = fmaf(lhb[widx][k + 0], w2s[(k + 0) * NF + lane], n0);
        n1 = fmaf(lhb[widx][k + 1], w2s[(k + 1) * NF + lane], n1);
        n2 = fmaf(lhb[widx][k + 2], w2s[(k + 2) * NF + lane], n2);
        n3 = fmaf(lhb[widx][k + 3], w2s[(k + 3) * NF + lane], n3);
    }
    float ma = ((m0 + m1) + (m2 + m3)) + b2[lane];
    float mb = ((n0 + n1) + (n2 + n3)) + b2[lane];
    tabp[g * NF + lane] = (uint32_t)bf16_bits(ma) | ((uint32_t)bf16_bits(mb) << 16);
}

// ---------------- kernel B: writhe per unordered edge + folded out=x copy -------
// Thread per (b, e) over the seg list. Packs t0(12b)|al(20b), stores ta[b][i][j]
// and mirror ta[b][j][i] (m symmetric). Prologue: out = x (kills init kernel).
__launch_bounds__(256)
__global__ void pass_ta2(const float* __restrict__ xyz, const int* __restrict__ seg,
                         const float* __restrict__ x, float* __restrict__ out,
                         uint32_t* __restrict__ ta, int P) {
    const int tid = blockIdx.x * 256 + threadIdx.x;
    if (tid < NB * N_ATOMS * NF) out[tid] = x[tid];     // out = x (coalesced)
    if (tid >= NB * P) return;
    const int b = tid / P;
    const int e = tid - b * P;

    int4 sv = ((const int4*)seg)[e];
    const int i = sv.x;
    const int j = sv.z;

    float w = compute_wr(xyz + b * (N_ATOMS * 3), i, j);
    float tf = (w + 1.0f) * ((float)(NT - 1) * 0.5f);    // same mapping R6..R11
    tf = fminf(fmaxf(tf, 0.0f), (float)(NT - 1));
    int t0 = (int)tf;
    t0 = (t0 > NT - 2) ? (NT - 2) : t0;
    float al = tf - (float)t0;

    uint32_t u = ((uint32_t)t0 << 20) | (uint32_t)(al * 1048575.0f);
    ta[(b << 18) + (i << 9) + j] = u;
    ta[(b << 18) + (j << 9) + i] = u;
}

// ---------------- kernel C: aggregation — fully static inner loop ---------------
// One wave per (b, dst, chunk) = 32768 waves (occ-proven R10/R11). Full unroll:
// ee is compile-time -> readlane(const) puts (toff, al) on the SALU side; VALU
// per iter = 2 bf16-unpack + sub + 2 fma. Guards wave-uniform (SALU branch).
__launch_bounds__(256)
__global__ void agg5(
        const float* __restrict__ x, const uint32_t* __restrict__ ta,
        const uint32_t* __restrict__ tabp, float* __restrict__ out) {
    const int lane = threadIdx.x & 63;
    const int gw = blockIdx.x * 4 + (threadIdx.x >> 6);   // 0..32767
    const int c  = gw & 7;
    const int dst = (gw >> 3) & (N_ATOMS - 1);
    const int b  = gw >> 12;

    // per-lane (src = c*64+lane) packed (t0, al) — one coalesced 256B load
    const uint32_t tav = ta[((size_t)b << 18) + (dst << 9) + (c << 6) + lane];
    const int   to_l = (int)(tav >> 20) << 6;             // t0 * 64 (dword index)
    const float al_l = (float)(tav & 0xFFFFFu) * (1.0f / 1048575.0f);

    if (dst >= NSEG) return;   // wave-uniform; kernel has no barriers

    const float* xc = x + ((size_t)b << 15) + (c << 12);  // x[b][c*64..][*]
    const int base = c << 6;
    float acc = 0.0f;

    #pragma unroll
    for (int ee = 0; ee < 64; ++ee) {
        const int se = base + ee;
        const bool ok = (se < dst - 1 || se > dst + 1) && (se <= NSEG - 1);  // uniform
        if (ok) {
            const int toff = __builtin_amdgcn_readlane(to_l, ee);             // SGPR
            const float alv = __uint_as_float(
                (unsigned)__builtin_amdgcn_readlane((int)__float_as_uint(al_l), ee));
            uint32_t mp = tabp[toff + lane];       // {bf16 m_t, bf16 m_{t+1}}, 256B
            float m0 = __uint_as_float(mp << 16);
            float m1 = __uint_as_float(mp & 0xFFFF0000u);
            float mv = fmaf(alv, m1 - m0, m0);
            acc = fmaf(mv, xc[(ee << 6) + lane], acc);
        }
    }
    atomicAdd(&out[((size_t)b << 15) + (dst << 6) + lane], acc);
}

// ---------------- fallback path (ws too small): R2 atomic kernel (proven) -------

__global__ void init_out_kernel(const float* __restrict__ x, float* __restrict__ out, int n) {
    int idx = blockIdx.x * blockDim.x + threadIdx.x;
    if (idx < n) out[idx] = x[idx];
}

__device__ __forceinline__ void compute_m(
        const float* __restrict__ pb, int i, int j,
        const float* __restrict__ W1, const float* __restrict__ b1,
        const float* __restrict__ W2, const float* __restrict__ b2,
        float* __restrict__ mout) {
    float wr = compute_wr(pb, i, j);
    float acc_[NBINS];
    {
        float tt = (wr + 1.0f) * 31.5f;
        #pragma unroll
        for (int k = 0; k < NBINS; ++k) {
            float d = tt - (float)k;
            acc_[k] = __expf(-d * d) * 0.8928571428571429f;
        }
    }
    float h_[NF];
    #pragma unroll
    for (int f = 0; f < NF; ++f) h_[f] = b1[f];
    #pragma unroll
    for (int k = 0; k < NBINS; ++k) {
        float r = acc_[k];
        #pragma unroll
        for (int f = 0; f < NF; ++f) h_[f] = fmaf(r, W1[k * NF + f], h_[f]);
    }
    #pragma unroll
    for (int f = 0; f < NF; ++f) h_[f] = fmaxf(h_[f], 0.01f * h_[f]);
    #pragma unroll
    for (int f = 0; f < NF; ++f) acc_[f] = b2[f];
    #pragma unroll
    for (int k = 0; k < NF; ++k) {
        float hk = h_[k];
        #pragma unroll
        for (int f = 0; f < NF; ++f) acc_[f] = fmaf(hk, W2[k * NF + f], acc_[f]);
    }
    #pragma unroll
    for (int f = 0; f < NF; ++f) mout[f] = acc_[f];
}

__launch_bounds__(256, 2)
__global__ void writhe_msg_atomic_kernel(
        const float* __restrict__ x, const float* __restrict__ xyz,
        const int* __restrict__ seg,
        const float* __restrict__ W1, const float* __restrict__ b1,
        const float* __restrict__ W2, const float* __restrict__ b2,
        float* __restrict__ out, int P, int n_tiles) {
    __shared__ __hip_bfloat16 lds_m[4][64 * 65];
    __shared__ int lds_i[4][64];
    __shared__ int lds_j[4][64];

    const int widx = threadIdx.x >> 6;
    const int lane = threadIdx.x & 63;
    const int wave_g = blockIdx.x * 4 + widx;
    const int b = wave_g / n_tiles;
    const int tile = wave_g - b * n_tiles;
    const int bc = (b < NB) ? b : 0;
    const int e = tile * 64 + lane;
    const bool valid = (b < NB) && (e < P);

    int4 sv = valid ? ((const int4*)seg)[e] : make_int4(0, 1, 2, 3);
    const int i = sv.x;
    const int j = sv.z;

    float m[NF];
    compute_m(xyz + bc * (N_ATOMS * 3), i, j, W1, b1, W2, b2, m);

    const float scale = valid ? 1.0f : 0.0f;
    #pragma unroll
    for (int f = 0; f < NF; ++f)
        lds_m[widx][lane * 65 + f] = __float2bfloat16(m[f] * scale);
    lds_i[widx][lane] = i;
    lds_j[widx][lane] = j;
    __syncthreads();

    const float* xb = x + bc * (N_ATOMS * NF);
    float* ob = out + bc * (N_ATOMS * NF);
    int cur_i = lds_i[widx][0];
    float acc_i = 0.0f;
    for (int ee = 0; ee < 64; ++ee) {
        int ie = lds_i[widx][ee];
        int je = lds_j[widx][ee];
        float mv = __bfloat162float(lds_m[widx][ee * 65 + lane]);
        float xi = xb[ie * NF + lane];
        float xj = xb[je * NF + lane];
        atomicAdd(&ob[je * NF + lane], mv * xi);
        if (ie != cur_i) {
            atomicAdd(&ob[cur_i * NF + lane], acc_i);
            acc_i = 0.0f;
            cur_i = ie;
        }
        acc_i = fmaf(mv, xj, acc_i);
    }
    atomicAdd(&ob[cur_i * NF + lane], acc_i);
}

extern "C" void kernel_launch(void* const* d_in, const int* in_sizes, int n_in,
                              void* d_out, int out_size, void* d_ws, size_t ws_size,
                              hipStream_t stream) {
    const float* x   = (const float*)d_in[0];
    const float* xyz = (const float*)d_in[1];
    const int*   seg = (const int*)d_in[2];
    const float* W1  = (const float*)d_in[3];
    const float* b1  = (const float*)d_in[4];
    const float* W2  = (const float*)d_in[5];
    const float* b2  = (const float*)d_in[6];
    float* out = (float*)d_out;

    const int P = in_sizes[2] / 4;              // 129795 edges
    const int n_tiles = (P + 63) / 64;          // 2029

    const size_t tabp_bytes = (size_t)NT * NF * sizeof(uint32_t);              // 1 MB
    const size_t ta_bytes   = (size_t)NB * N_ATOMS * N_ATOMS * sizeof(uint32_t); // 8 MB
    const size_t need_ws = tabp_bytes + ta_bytes;                              // 9 MB

    if (ws_size >= need_ws) {
        uint32_t* tabp = (uint32_t*)d_ws;
        uint32_t* ta   = (uint32_t*)((char*)d_ws + tabp_bytes);

        hipLaunchKernelGGL(build_tab4, dim3(NT / 4), dim3(256), 0, stream,
                           W1, b1, W2, b2, tabp);

        hipLaunchKernelGGL(pass_ta2, dim3((NB * P + 255) / 256), dim3(256), 0, stream,
                           xyz, seg, x, out, ta, P);

        hipLaunchKernelGGL(agg5, dim3((NB * N_ATOMS * 8) / 4), dim3(256), 0, stream,
                           x, ta, tabp, out);
    } else {
        const int n = out_size;
        hipLaunchKernelGGL(init_out_kernel, dim3((n + 255) / 256), dim3(256), 0, stream,
                           x, out, n);
        const int total_waves = NB * n_tiles;
        const int blocks = (total_waves + 3) / 4;
        hipLaunchKernelGGL(writhe_msg_atomic_kernel, dim3(blocks), dim3(256), 0, stream,
                           x, xyz, seg, W1, b1, W2, b2, out, P, n_tiles);
    }
}

// Round 13
// 138.856 us; speedup vs baseline: 1.3147x; 1.3147x over previous
//
#include <hip/hip_runtime.h>
#include <hip/hip_bf16.h>
#include <math.h>
#include <stdint.h>

#define N_ATOMS 512
#define NF 64
#define NB 8
#define NBINS 64
#define NSEG 511     // segment nodes 0..510; valid pairs i<j, j>=i+2
#define NTF 16384    // fine m(wr) grid (nearest-neighbor; sentinel row = NTF)
#define NSENT 2554   // invalid (dst,src) slots per batch needing the zero-sentinel

__device__ __forceinline__ float dot3(float ax, float ay, float az,
                                      float bx, float by, float bz) {
    return fmaf(ax, bx, fmaf(ay, by, az * bz));
}

// writhe scalar for edge (i,j), i<j — verified (R2..R12 absmax 0.0625)
__device__ __forceinline__ float compute_wr(const float* __restrict__ pb, int i, int j) {
    float p0x = pb[3*i+0], p0y = pb[3*i+1], p0z = pb[3*i+2];
    float p1x = pb[3*i+3], p1y = pb[3*i+4], p1z = pb[3*i+5];
    float p2x = pb[3*j+0], p2y = pb[3*j+1], p2z = pb[3*j+2];
    float p3x = pb[3*j+3], p3y = pb[3*j+4], p3z = pb[3*j+5];

    float d0x = p2x-p0x, d0y = p2y-p0y, d0z = p2z-p0z;
    float d1x = p3x-p0x, d1y = p3y-p0y, d1z = p3z-p0z;
    float d2x = p2x-p1x, d2y = p2y-p1y, d2z = p2z-p1z;
    float d3x = p3x-p1x, d3y = p3y-p1y, d3z = p3z-p1z;
    {
        float n0 = rsqrtf(dot3(d0x,d0y,d0z,d0x,d0y,d0z)); d0x*=n0; d0y*=n0; d0z*=n0;
        float n1 = rsqrtf(dot3(d1x,d1y,d1z,d1x,d1y,d1z)); d1x*=n1; d1y*=n1; d1z*=n1;
        float n2 = rsqrtf(dot3(d2x,d2y,d2z,d2x,d2y,d2z)); d2x*=n2; d2y*=n2; d2z*=n2;
        float n3 = rsqrtf(dot3(d3x,d3y,d3z,d3x,d3y,d3z)); d3x*=n3; d3y*=n3; d3z*=n3;
    }
    float c0x = d0y*d1z - d0z*d1y, c0y = d0z*d1x - d0x*d1z, c0z = d0x*d1y - d0y*d1x;
    float c1x = d1y*d3z - d1z*d3y, c1y = d1z*d3x - d1x*d3z, c1z = d1x*d3y - d1y*d3x;
    float c3x = d2y*d0z - d2z*d0y, c3y = d2z*d0x - d2x*d0z, c3z = d2x*d0y - d2y*d0x;
    {
        float n0 = rsqrtf(dot3(c0x,c0y,c0z,c0x,c0y,c0z)); c0x*=n0; c0y*=n0; c0z*=n0;
        float n1 = rsqrtf(dot3(c1x,c1y,c1z,c1x,c1y,c1z)); c1x*=n1; c1y*=n1; c1z*=n1;
        float n3 = rsqrtf(dot3(c3x,c3y,c3z,c3x,c3y,c3z)); c3x*=n3; c3y*=n3; c3z*=n3;
    }
    float t0 = fminf(fmaxf(dot3(c0x,c0y,c0z, c1x,c1y,c1z), -1.f), 1.f);
    float t1 = fminf(fmaxf(dot3(c1x,c1y,c1z, c3x,c3y,c3z), -1.f), 1.f);
    float t3 = fminf(fmaxf(dot3(c3x,c3y,c3z, c0x,c0y,c0z), -1.f), 1.f);
    float omega = asinf(t0) + asinf(t1) + asinf(t3) + 1.5707963267948966f;
    float ex = p3x-p2x, ey = p3y-p2y, ez = p3z-p2z;
    float fx = p1x-p0x, fy = p1y-p0y, fz = p1z-p0z;
    float gx = ey*fz - ez*fy, gy = ez*fx - ex*fz, gz = ex*fy - ey*fx;
    float sgd = dot3(gx,gy,gz, d0x,d0y,d0z);
    float sgn = (sgd > 0.f) ? 1.f : ((sgd < 0.f) ? -1.f : 0.f);
    return omega * sgn * 0.15915494309189535f;
}

// ---------------- launch 1: mega-prepass (one kernel, drain amortized) ----------
// blocks [0, NTF/4): fine-table build — one wave per grid point t, lane = feature,
//   exact fp32 MLP (ILP-4 partial sums), W rows from global (L2-hot). Wave t==0
//   also zeroes the sentinel row NTF.
// blocks [NTF/4, ...): out = x copy; per-edge writhe -> nearest fine index
//   (pre-shifted dword offset) stored to ta[b][i][j] + mirror; sentinel fill of
//   the 2554 invalid slots per batch with offset NTF*64 (zero row).
__launch_bounds__(256)
__global__ void prepass(
        const float* __restrict__ xyz, const int* __restrict__ seg,
        const float* __restrict__ x, float* __restrict__ out,
        const float* __restrict__ W1, const float* __restrict__ b1,
        const float* __restrict__ W2, const float* __restrict__ b2,
        float* __restrict__ tabf, uint32_t* __restrict__ ta, int P) {
    __shared__ float lh[4][64];

    if (blockIdx.x < NTF / 4) {
        // ---------------- fine-table build ----------------
        const int widx = threadIdx.x >> 6;
        const int lane = threadIdx.x & 63;
        const int g = blockIdx.x * 4 + widx;

        float wr = -1.0f + (2.0f / (float)(NTF - 1)) * (float)g;
        float tt = (wr + 1.0f) * 31.5f;   // same rbf mapping as R2..R12 (proven)

        float h0 = 0.f, h1 = 0.f, h2 = 0.f, h3 = 0.f;
        #pragma unroll
        for (int k = 0; k < NBINS; k += 4) {
            float d0 = tt - (float)(k + 0);
            float d1 = tt - (float)(k + 1);
            float d2 = tt - (float)(k + 2);
            float d3 = tt - (float)(k + 3);
            h0 = fmaf(__expf(-d0 * d0) * 0.8928571428571429f, W1[(k + 0) * NF + lane], h0);
            h1 = fmaf(__expf(-d1 * d1) * 0.8928571428571429f, W1[(k + 1) * NF + lane], h1);
            h2 = fmaf(__expf(-d2 * d2) * 0.8928571428571429f, W1[(k + 2) * NF + lane], h2);
            h3 = fmaf(__expf(-d3 * d3) * 0.8928571428571429f, W1[(k + 3) * NF + lane], h3);
        }
        float h = ((h0 + h1) + (h2 + h3)) + b1[lane];
        h = fmaxf(h, 0.01f * h);
        lh[widx][lane] = h;
        __syncthreads();

        float m0 = 0.f, m1 = 0.f, m2 = 0.f, m3 = 0.f;
        #pragma unroll
        for (int k = 0; k < NF; k += 4) {
            m0 = fmaf(lh[widx][k + 0], W2[(k + 0) * NF + lane], m0);
            m1 = fmaf(lh[widx][k + 1], W2[(k + 1) * NF + lane], m1);
            m2 = fmaf(lh[widx][k + 2], W2[(k + 2) * NF + lane], m2);
            m3 = fmaf(lh[widx][k + 3], W2[(k + 3) * NF + lane], m3);
        }
        float m = ((m0 + m1) + (m2 + m3)) + b2[lane];
        tabf[g * NF + lane] = m;
        if (g == 0) tabf[NTF * NF + lane] = 0.0f;   // sentinel zero row
    } else {
        // ---------------- copy + edge indices + sentinels ----------------
        const int tid2 = (blockIdx.x - NTF / 4) * 256 + threadIdx.x;

        if (tid2 < NB * N_ATOMS * NF) out[tid2] = x[tid2];   // out = x (coalesced)

        if (tid2 < NB * P) {
            const int b = tid2 / P;
            const int e = tid2 - b * P;
            int4 sv = ((const int4*)seg)[e];
            const int i = sv.x;
            const int j = sv.z;

            float w  = compute_wr(xyz + b * (N_ATOMS * 3), i, j);
            float tf = (w + 1.0f) * ((float)(NTF - 1) * 0.5f);
            tf = fminf(fmaxf(tf, 0.0f), (float)(NTF - 1));
            int t0 = (int)(tf + 0.5f);                 // nearest
            t0 = (t0 > NTF - 1) ? (NTF - 1) : t0;
            uint32_t u = (uint32_t)t0 << 6;            // pre-shifted dword offset

            ta[(b << 18) + (i << 9) + j] = u;
            ta[(b << 18) + (j << 9) + i] = u;          // mirror (m symmetric)
        } else if (tid2 < NB * P + NB * NSENT) {
            const int idx = tid2 - NB * P;
            const int b = idx / NSENT;
            const int k = idx - b * NSENT;
            int d, s;
            if      (k < 512)  { d = k;        s = k;     }   // diagonal
            else if (k < 1023) { d = k - 512;  s = d + 1; }   // upper band
            else if (k < 1534) { s = k - 1023; d = s + 1; }   // lower band
            else if (k < 2044) { d = k - 1534; s = NSEG;  }   // col 511 (d<=509)
            else               { s = k - 2044; d = NSEG;  }   // row 511 (s<=509)
            ta[(b << 18) + (d << 9) + s] = (uint32_t)NTF << 6;  // -> zero row
        }
    }
}

// ---------------- launch 2: aggregation — guard-free minimal inner loop ---------
// One wave per (b, dst, chunk) = 32768 waves. Per iter: readlane(const) -> SGPR
// row offset; one f32 table load; one x load; one fma. Invalid srcs hit the zero
// sentinel row -> contribute exactly 0.0 (acc unchanged). No branches, no lerp.
__launch_bounds__(256)
__global__ void agg7(
        const float* __restrict__ x, const uint32_t* __restrict__ ta,
        const float* __restrict__ tabf, float* __restrict__ out) {
    const int lane = threadIdx.x & 63;
    const int gw = blockIdx.x * 4 + (threadIdx.x >> 6);   // 0..32767
    const int c  = gw & 7;
    const int dst = (gw >> 3) & (N_ATOMS - 1);
    const int b  = gw >> 12;

    if (dst >= NSEG) return;   // wave-uniform; row 511 is all-sentinel anyway

    // per-lane (src = c*64+lane) table row offset — one coalesced 256B load
    const int tav = (int)ta[((size_t)b << 18) + (dst << 9) + (c << 6) + lane];

    const float* xc = x + ((size_t)b << 15) + (c << 12);  // x[b][c*64..][*]
    float acc = 0.0f;

    #pragma unroll
    for (int ee = 0; ee < 64; ++ee) {
        const int off = __builtin_amdgcn_readlane(tav, ee);   // SGPR dword offset
        const float mv = tabf[off + lane];                    // m[src][lane] (or 0)
        acc = fmaf(mv, xc[(ee << 6) + lane], acc);
    }
    atomicAdd(&out[((size_t)b << 15) + (dst << 6) + lane], acc);
}

// ---------------- fallback path (ws too small): R2 atomic kernel (proven) -------

__global__ void init_out_kernel(const float* __restrict__ x, float* __restrict__ out, int n) {
    int idx = blockIdx.x * blockDim.x + threadIdx.x;
    if (idx < n) out[idx] = x[idx];
}

__device__ __forceinline__ void compute_m(
        const float* __restrict__ pb, int i, int j,
        const float* __restrict__ W1, const float* __restrict__ b1,
        const float* __restrict__ W2, const float* __restrict__ b2,
        float* __restrict__ mout) {
    float wr = compute_wr(pb, i, j);
    float acc_[NBINS];
    {
        float tt = (wr + 1.0f) * 31.5f;
        #pragma unroll
        for (int k = 0; k < NBINS; ++k) {
            float d = tt - (float)k;
            acc_[k] = __expf(-d * d) * 0.8928571428571429f;
        }
    }
    float h_[NF];
    #pragma unroll
    for (int f = 0; f < NF; ++f) h_[f] = b1[f];
    #pragma unroll
    for (int k = 0; k < NBINS; ++k) {
        float r = acc_[k];
        #pragma unroll
        for (int f = 0; f < NF; ++f) h_[f] = fmaf(r, W1[k * NF + f], h_[f]);
    }
    #pragma unroll
    for (int f = 0; f < NF; ++f) h_[f] = fmaxf(h_[f], 0.01f * h_[f]);
    #pragma unroll
    for (int f = 0; f < NF; ++f) acc_[f] = b2[f];
    #pragma unroll
    for (int k = 0; k < NF; ++k) {
        float hk = h_[k];
        #pragma unroll
        for (int f = 0; f < NF; ++f) acc_[f] = fmaf(hk, W2[k * NF + f], acc_[f]);
    }
    #pragma unroll
    for (int f = 0; f < NF; ++f) mout[f] = acc_[f];
}

__launch_bounds__(256, 2)
__global__ void writhe_msg_atomic_kernel(
        const float* __restrict__ x, const float* __restrict__ xyz,
        const int* __restrict__ seg,
        const float* __restrict__ W1, const float* __restrict__ b1,
        const float* __restrict__ W2, const float* __restrict__ b2,
        float* __restrict__ out, int P, int n_tiles) {
    __shared__ __hip_bfloat16 lds_m[4][64 * 65];
    __shared__ int lds_i[4][64];
    __shared__ int lds_j[4][64];

    const int widx = threadIdx.x >> 6;
    const int lane = threadIdx.x & 63;
    const int wave_g = blockIdx.x * 4 + widx;
    const int b = wave_g / n_tiles;
    const int tile = wave_g - b * n_tiles;
    const int bc = (b < NB) ? b : 0;
    const int e = tile * 64 + lane;
    const bool valid = (b < NB) && (e < P);

    int4 sv = valid ? ((const int4*)seg)[e] : make_int4(0, 1, 2, 3);
    const int i = sv.x;
    const int j = sv.z;

    float m[NF];
    compute_m(xyz + bc * (N_ATOMS * 3), i, j, W1, b1, W2, b2, m);

    const float scale = valid ? 1.0f : 0.0f;
    #pragma unroll
    for (int f = 0; f < NF; ++f)
        lds_m[widx][lane * 65 + f] = __float2bfloat16(m[f] * scale);
    lds_i[widx][lane] = i;
    lds_j[widx][lane] = j;
    __syncthreads();

    const float* xb = x + bc * (N_ATOMS * NF);
    float* ob = out + bc * (N_ATOMS * NF);
    int cur_i = lds_i[widx][0];
    float acc_i = 0.0f;
    for (int ee = 0; ee < 64; ++ee) {
        int ie = lds_i[widx][ee];
        int je = lds_j[widx][ee];
        float mv = __bfloat162float(lds_m[widx][ee * 65 + lane]);
        float xi = xb[ie * NF + lane];
        float xj = xb[je * NF + lane];
        atomicAdd(&ob[je * NF + lane], mv * xi);
        if (ie != cur_i) {
            atomicAdd(&ob[cur_i * NF + lane], acc_i);
            acc_i = 0.0f;
            cur_i = ie;
        }
        acc_i = fmaf(mv, xj, acc_i);
    }
    atomicAdd(&ob[cur_i * NF + lane], acc_i);
}

extern "C" void kernel_launch(void* const* d_in, const int* in_sizes, int n_in,
                              void* d_out, int out_size, void* d_ws, size_t ws_size,
                              hipStream_t stream) {
    const float* x   = (const float*)d_in[0];
    const float* xyz = (const float*)d_in[1];
    const int*   seg = (const int*)d_in[2];
    const float* W1  = (const float*)d_in[3];
    const float* b1  = (const float*)d_in[4];
    const float* W2  = (const float*)d_in[5];
    const float* b2  = (const float*)d_in[6];
    float* out = (float*)d_out;

    const int P = in_sizes[2] / 4;              // 129795 edges
    const int n_tiles = (P + 63) / 64;          // 2029

    const size_t tabf_bytes = (size_t)(NTF + 1) * NF * sizeof(float);            // 4.2 MB
    const size_t ta_bytes   = (size_t)NB * N_ATOMS * N_ATOMS * sizeof(uint32_t); // 8 MB
    const size_t need_ws = tabf_bytes + ta_bytes;

    if (ws_size >= need_ws) {
        float*    tabf = (float*)d_ws;
        uint32_t* ta   = (uint32_t*)((char*)d_ws + tabf_bytes);

        const int nbuild = NTF / 4;                                   // 4096 blocks
        const int npass_th = NB * P + NB * NSENT;                     // 1,058,792
        const int npass = (npass_th + 255) / 256;                     // 4136 blocks
        hipLaunchKernelGGL(prepass, dim3(nbuild + npass), dim3(256), 0, stream,
                           xyz, seg, x, out, W1, b1, W2, b2, tabf, ta, P);

        hipLaunchKernelGGL(agg7, dim3((NB * N_ATOMS * 8) / 4), dim3(256), 0, stream,
                           x, ta, tabf, out);
    } else {
        const int n = out_size;
        hipLaunchKernelGGL(init_out_kernel, dim3((n + 255) / 256), dim3(256), 0, stream,
                           x, out, n);
        const int total_waves = NB * n_tiles;
        const int blocks = (total_waves + 3) / 4;
        hipLaunchKernelGGL(writhe_msg_atomic_kernel, dim3(blocks), dim3(256), 0, stream,
                           x, xyz, seg, W1, b1, W2, b2, out, P, n_tiles);
    }
}

// Round 14
// 113.427 us; speedup vs baseline: 1.6094x; 1.2242x over previous
//
#include <hip/hip_runtime.h>
#include <hip/hip_bf16.h>
#include <math.h>
#include <stdint.h>

#define N_ATOMS 512
#define NF 64
#define NB 8
#define NBINS 64
#define NSEG 511     // segment nodes 0..510; valid pairs i<j, j>=i+2
#define NTF 8192     // fine m(wr) grid (nearest; bf16; sentinel row = NTF)
#define NSENT 2554   // invalid (dst,src) slots per batch needing the zero-sentinel

__device__ __forceinline__ float dot3(float ax, float ay, float az,
                                      float bx, float by, float bz) {
    return fmaf(ax, bx, fmaf(ay, by, az * bz));
}

__device__ __forceinline__ uint16_t bf16_bits(float f) {
    union { __hip_bfloat16 h; uint16_t u; } cv;
    cv.h = __float2bfloat16(f);
    return cv.u;
}

// writhe scalar for edge (i,j), i<j — verified (R2..R13 absmax 0.0625)
__device__ __forceinline__ float compute_wr(const float* __restrict__ pb, int i, int j) {
    float p0x = pb[3*i+0], p0y = pb[3*i+1], p0z = pb[3*i+2];
    float p1x = pb[3*i+3], p1y = pb[3*i+4], p1z = pb[3*i+5];
    float p2x = pb[3*j+0], p2y = pb[3*j+1], p2z = pb[3*j+2];
    float p3x = pb[3*j+3], p3y = pb[3*j+4], p3z = pb[3*j+5];

    float d0x = p2x-p0x, d0y = p2y-p0y, d0z = p2z-p0z;
    float d1x = p3x-p0x, d1y = p3y-p0y, d1z = p3z-p0z;
    float d2x = p2x-p1x, d2y = p2y-p1y, d2z = p2z-p1z;
    float d3x = p3x-p1x, d3y = p3y-p1y, d3z = p3z-p1z;
    {
        float n0 = rsqrtf(dot3(d0x,d0y,d0z,d0x,d0y,d0z)); d0x*=n0; d0y*=n0; d0z*=n0;
        float n1 = rsqrtf(dot3(d1x,d1y,d1z,d1x,d1y,d1z)); d1x*=n1; d1y*=n1; d1z*=n1;
        float n2 = rsqrtf(dot3(d2x,d2y,d2z,d2x,d2y,d2z)); d2x*=n2; d2y*=n2; d2z*=n2;
        float n3 = rsqrtf(dot3(d3x,d3y,d3z,d3x,d3y,d3z)); d3x*=n3; d3y*=n3; d3z*=n3;
    }
    float c0x = d0y*d1z - d0z*d1y, c0y = d0z*d1x - d0x*d1z, c0z = d0x*d1y - d0y*d1x;
    float c1x = d1y*d3z - d1z*d3y, c1y = d1z*d3x - d1x*d3z, c1z = d1x*d3y - d1y*d3x;
    float c3x = d2y*d0z - d2z*d0y, c3y = d2z*d0x - d2x*d0z, c3z = d2x*d0y - d2y*d0x;
    {
        float n0 = rsqrtf(dot3(c0x,c0y,c0z,c0x,c0y,c0z)); c0x*=n0; c0y*=n0; c0z*=n0;
        float n1 = rsqrtf(dot3(c1x,c1y,c1z,c1x,c1y,c1z)); c1x*=n1; c1y*=n1; c1z*=n1;
        float n3 = rsqrtf(dot3(c3x,c3y,c3z,c3x,c3y,c3z)); c3x*=n3; c3y*=n3; c3z*=n3;
    }
    float t0 = fminf(fmaxf(dot3(c0x,c0y,c0z, c1x,c1y,c1z), -1.f), 1.f);
    float t1 = fminf(fmaxf(dot3(c1x,c1y,c1z, c3x,c3y,c3z), -1.f), 1.f);
    float t3 = fminf(fmaxf(dot3(c3x,c3y,c3z, c0x,c0y,c0z), -1.f), 1.f);
    float omega = asinf(t0) + asinf(t1) + asinf(t3) + 1.5707963267948966f;
    float ex = p3x-p2x, ey = p3y-p2y, ez = p3z-p2z;
    float fx = p1x-p0x, fy = p1y-p0y, fz = p1z-p0z;
    float gx = ey*fz - ez*fy, gy = ez*fx - ex*fz, gz = ex*fy - ey*fx;
    float sgd = dot3(gx,gy,gz, d0x,d0y,d0z);
    float sgn = (sgd > 0.f) ? 1.f : ((sgd < 0.f) ? -1.f : 0.f);
    return omega * sgn * 0.15915494309189535f;
}

// ---------------- launch 1: mega-prepass (one kernel, drain amortized) ----------
// blocks [0, NTF/4): bf16 fine-table build (exact fp32 MLP, ILP-4; wave g==0 also
//   zeroes sentinel row NTF). blocks [NTF/4, ...): out=x copy; per-edge writhe ->
//   nearest index (pre-shifted element offset) to ta[b][i][j]+mirror; sentinel
//   fill of the 2554 invalid slots per batch -> zero row.
__launch_bounds__(256)
__global__ void prepass(
        const float* __restrict__ xyz, const int* __restrict__ seg,
        const float* __restrict__ x, float* __restrict__ out,
        const float* __restrict__ W1, const float* __restrict__ b1,
        const float* __restrict__ W2, const float* __restrict__ b2,
        uint16_t* __restrict__ tabh, uint32_t* __restrict__ ta, int P) {
    __shared__ float lh[4][64];

    if (blockIdx.x < NTF / 4) {
        const int widx = threadIdx.x >> 6;
        const int lane = threadIdx.x & 63;
        const int g = blockIdx.x * 4 + widx;

        float wr = -1.0f + (2.0f / (float)(NTF - 1)) * (float)g;
        float tt = (wr + 1.0f) * 31.5f;   // same rbf mapping R2..R13 (proven)

        float h0 = 0.f, h1 = 0.f, h2 = 0.f, h3 = 0.f;
        #pragma unroll
        for (int k = 0; k < NBINS; k += 4) {
            float d0 = tt - (float)(k + 0);
            float d1 = tt - (float)(k + 1);
            float d2 = tt - (float)(k + 2);
            float d3 = tt - (float)(k + 3);
            h0 = fmaf(__expf(-d0 * d0) * 0.8928571428571429f, W1[(k + 0) * NF + lane], h0);
            h1 = fmaf(__expf(-d1 * d1) * 0.8928571428571429f, W1[(k + 1) * NF + lane], h1);
            h2 = fmaf(__expf(-d2 * d2) * 0.8928571428571429f, W1[(k + 2) * NF + lane], h2);
            h3 = fmaf(__expf(-d3 * d3) * 0.8928571428571429f, W1[(k + 3) * NF + lane], h3);
        }
        float h = ((h0 + h1) + (h2 + h3)) + b1[lane];
        h = fmaxf(h, 0.01f * h);
        lh[widx][lane] = h;
        __syncthreads();

        float m0 = 0.f, m1 = 0.f, m2 = 0.f, m3 = 0.f;
        #pragma unroll
        for (int k = 0; k < NF; k += 4) {
            m0 = fmaf(lh[widx][k + 0], W2[(k + 0) * NF + lane], m0);
            m1 = fmaf(lh[widx][k + 1], W2[(k + 1) * NF + lane], m1);
            m2 = fmaf(lh[widx][k + 2], W2[(k + 2) * NF + lane], m2);
            m3 = fmaf(lh[widx][k + 3], W2[(k + 3) * NF + lane], m3);
        }
        float m = ((m0 + m1) + (m2 + m3)) + b2[lane];
        tabh[g * NF + lane] = bf16_bits(m);
        if (g == 0) tabh[NTF * NF + lane] = 0;     // sentinel zero row
    } else {
        const int tid2 = (blockIdx.x - NTF / 4) * 256 + threadIdx.x;

        if (tid2 < NB * N_ATOMS * NF) out[tid2] = x[tid2];   // out = x (coalesced)

        if (tid2 < NB * P) {
            const int b = tid2 / P;
            const int e = tid2 - b * P;
            int4 sv = ((const int4*)seg)[e];
            const int i = sv.x;
            const int j = sv.z;

            float w  = compute_wr(xyz + b * (N_ATOMS * 3), i, j);
            float tf = (w + 1.0f) * ((float)(NTF - 1) * 0.5f);
            tf = fminf(fmaxf(tf, 0.0f), (float)(NTF - 1));
            int t0 = (int)(tf + 0.5f);                 // nearest
            t0 = (t0 > NTF - 1) ? (NTF - 1) : t0;
            uint32_t u = (uint32_t)t0 << 6;            // pre-shifted element offset

            ta[(b << 18) + (i << 9) + j] = u;
            ta[(b << 18) + (j << 9) + i] = u;          // mirror (m symmetric)
        } else if (tid2 < NB * P + NB * NSENT) {
            const int idx = tid2 - NB * P;
            const int b = idx / NSENT;
            const int k = idx - b * NSENT;
            int d, s;
            if      (k < 512)  { d = k;        s = k;     }   // diagonal
            else if (k < 1023) { d = k - 512;  s = d + 1; }   // upper band
            else if (k < 1534) { s = k - 1023; d = s + 1; }   // lower band
            else if (k < 2044) { d = k - 1534; s = NSEG;  }   // col 511 (d<=509)
            else               { s = k - 2044; d = NSEG;  }   // row 511 (s<=509)
            ta[(b << 18) + (d << 9) + s] = (uint32_t)NTF << 6;  // -> zero row
        }
    }
}

// ---------------- launch 2: aggregation — LDS x-share + bf16 table --------------
// Block = 4 waves sharing (b, chunk c), dst = dgrp*4 + widx. The 16 KB x-chunk is
// staged to LDS once (÷4 x L2 traffic); tab reads are bf16 (÷2 tab L2 traffic,
// 1.05 MB table is L2-resident per XCD). Inner iter: readlane(const) -> SGPR row
// offset; ushort tab load + shl; LDS x read (stride-1, conflict-free); fma.
// Invalid srcs hit the zero sentinel row -> contribute exactly 0.
__launch_bounds__(256)
__global__ void agg8(
        const float* __restrict__ x, const uint32_t* __restrict__ ta,
        const uint16_t* __restrict__ tabh, float* __restrict__ out) {
    __shared__ float lds_x[4096];   // x[b][c*64 .. c*64+63][0..63]

    const int widx = threadIdx.x >> 6;
    const int lane = threadIdx.x & 63;
    const int bid = blockIdx.x;                 // 0..8191
    const int c    = bid & 7;
    const int dgrp = (bid >> 3) & 127;
    const int b    = bid >> 10;
    const int dst  = dgrp * 4 + widx;

    // ---- cooperative x-chunk staging (coalesced) ----
    const float* xc = x + ((size_t)b << 15) + (c << 12);
    #pragma unroll
    for (int k = 0; k < 16; ++k)
        lds_x[k * 256 + threadIdx.x] = xc[k * 256 + threadIdx.x];
    __syncthreads();

    if (dst < NSEG) {
        // per-lane (src = c*64+lane) table row offset — one coalesced 256B load
        const int tav = (int)ta[((size_t)b << 18) + (dst << 9) + (c << 6) + lane];

        float acc = 0.0f;
        #pragma unroll
        for (int ee = 0; ee < 64; ++ee) {
            const int off = __builtin_amdgcn_readlane(tav, ee);   // SGPR elem offset
            const float mv = __uint_as_float((uint32_t)tabh[off + lane] << 16);
            acc = fmaf(mv, lds_x[(ee << 6) + lane], acc);
        }
        atomicAdd(&out[((size_t)b << 15) + (dst << 6) + lane], acc);
    }
}

// ---------------- fallback path (ws too small): R2 atomic kernel (proven) -------

__global__ void init_out_kernel(const float* __restrict__ x, float* __restrict__ out, int n) {
    int idx = blockIdx.x * blockDim.x + threadIdx.x;
    if (idx < n) out[idx] = x[idx];
}

__device__ __forceinline__ void compute_m(
        const float* __restrict__ pb, int i, int j,
        const float* __restrict__ W1, const float* __restrict__ b1,
        const float* __restrict__ W2, const float* __restrict__ b2,
        float* __restrict__ mout) {
    float wr = compute_wr(pb, i, j);
    float acc_[NBINS];
    {
        float tt = (wr + 1.0f) * 31.5f;
        #pragma unroll
        for (int k = 0; k < NBINS; ++k) {
            float d = tt - (float)k;
            acc_[k] = __expf(-d * d) * 0.8928571428571429f;
        }
    }
    float h_[NF];
    #pragma unroll
    for (int f = 0; f < NF; ++f) h_[f] = b1[f];
    #pragma unroll
    for (int k = 0; k < NBINS; ++k) {
        float r = acc_[k];
        #pragma unroll
        for (int f = 0; f < NF; ++f) h_[f] = fmaf(r, W1[k * NF + f], h_[f]);
    }
    #pragma unroll
    for (int f = 0; f < NF; ++f) h_[f] = fmaxf(h_[f], 0.01f * h_[f]);
    #pragma unroll
    for (int f = 0; f < NF; ++f) acc_[f] = b2[f];
    #pragma unroll
    for (int k = 0; k < NF; ++k) {
        float hk = h_[k];
        #pragma unroll
        for (int f = 0; f < NF; ++f) acc_[f] = fmaf(hk, W2[k * NF + f], acc_[f]);
    }
    #pragma unroll
    for (int f = 0; f < NF; ++f) mout[f] = acc_[f];
}

__launch_bounds__(256, 2)
__global__ void writhe_msg_atomic_kernel(
        const float* __restrict__ x, const float* __restrict__ xyz,
        const int* __restrict__ seg,
        const float* __restrict__ W1, const float* __restrict__ b1,
        const float* __restrict__ W2, const float* __restrict__ b2,
        float* __restrict__ out, int P, int n_tiles) {
    __shared__ __hip_bfloat16 lds_m[4][64 * 65];
    __shared__ int lds_i[4][64];
    __shared__ int lds_j[4][64];

    const int widx = threadIdx.x >> 6;
    const int lane = threadIdx.x & 63;
    const int wave_g = blockIdx.x * 4 + widx;
    const int b = wave_g / n_tiles;
    const int tile = wave_g - b * n_tiles;
    const int bc = (b < NB) ? b : 0;
    const int e = tile * 64 + lane;
    const bool valid = (b < NB) && (e < P);

    int4 sv = valid ? ((const int4*)seg)[e] : make_int4(0, 1, 2, 3);
    const int i = sv.x;
    const int j = sv.z;

    float m[NF];
    compute_m(xyz + bc * (N_ATOMS * 3), i, j, W1, b1, W2, b2, m);

    const float scale = valid ? 1.0f : 0.0f;
    #pragma unroll
    for (int f = 0; f < NF; ++f)
        lds_m[widx][lane * 65 + f] = __float2bfloat16(m[f] * scale);
    lds_i[widx][lane] = i;
    lds_j[widx][lane] = j;
    __syncthreads();

    const float* xb = x + bc * (N_ATOMS * NF);
    float* ob = out + bc * (N_ATOMS * NF);
    int cur_i = lds_i[widx][0];
    float acc_i = 0.0f;
    for (int ee = 0; ee < 64; ++ee) {
        int ie = lds_i[widx][ee];
        int je = lds_j[widx][ee];
        float mv = __bfloat162float(lds_m[widx][ee * 65 + lane]);
        float xi = xb[ie * NF + lane];
        float xj = xb[je * NF + lane];
        atomicAdd(&ob[je * NF + lane], mv * xi);
        if (ie != cur_i) {
            atomicAdd(&ob[cur_i * NF + lane], acc_i);
            acc_i = 0.0f;
            cur_i = ie;
        }
        acc_i = fmaf(mv, xj, acc_i);
    }
    atomicAdd(&ob[cur_i * NF + lane], acc_i);
}

extern "C" void kernel_launch(void* const* d_in, const int* in_sizes, int n_in,
                              void* d_out, int out_size, void* d_ws, size_t ws_size,
                              hipStream_t stream) {
    const float* x   = (const float*)d_in[0];
    const float* xyz = (const float*)d_in[1];
    const int*   seg = (const int*)d_in[2];
    const float* W1  = (const float*)d_in[3];
    const float* b1  = (const float*)d_in[4];
    const float* W2  = (const float*)d_in[5];
    const float* b2  = (const float*)d_in[6];
    float* out = (float*)d_out;

    const int P = in_sizes[2] / 4;              // 129795 edges
    const int n_tiles = (P + 63) / 64;          // 2029

    const size_t tabh_bytes = (size_t)(NTF + 1) * NF * sizeof(uint16_t);         // 1.05 MB
    const size_t ta_bytes   = (size_t)NB * N_ATOMS * N_ATOMS * sizeof(uint32_t); // 8 MB
    const size_t need_ws = tabh_bytes + ta_bytes;

    if (ws_size >= need_ws) {
        uint16_t* tabh = (uint16_t*)d_ws;
        uint32_t* ta   = (uint32_t*)((char*)d_ws + tabh_bytes);

        const int nbuild = NTF / 4;                                   // 2048 blocks
        const int npass_th = NB * P + NB * NSENT;                     // 1,058,792
        const int npass = (npass_th + 255) / 256;                     // 4136 blocks
        hipLaunchKernelGGL(prepass, dim3(nbuild + npass), dim3(256), 0, stream,
                           xyz, seg, x, out, W1, b1, W2, b2, tabh, ta, P);

        hipLaunchKernelGGL(agg8, dim3(NB * 128 * 8), dim3(256), 0, stream,
                           x, ta, tabh, out);
    } else {
        const int n = out_size;
        hipLaunchKernelGGL(init_out_kernel, dim3((n + 255) / 256), dim3(256), 0, stream,
                           x, out, n);
        const int total_waves = NB * n_tiles;
        const int blocks = (total_waves + 3) / 4;
        hipLaunchKernelGGL(writhe_msg_atomic_kernel, dim3(blocks), dim3(256), 0, stream,
                           x, xyz, seg, W1, b1, W2, b2, out, P, n_tiles);
    }
}

// Round 15
// 110.952 us; speedup vs baseline: 1.6453x; 1.0223x over previous
//
#include <hip/hip_runtime.h>
#include <hip/hip_bf16.h>
#include <math.h>
#include <stdint.h>

#define N_ATOMS 512
#define NF 64
#define NB 8
#define NBINS 64
#define NSEG 511     // segment nodes 0..510; valid pairs i<j, j>=i+2
#define NTF 8192     // fine m(wr) grid (nearest; bf16; sentinel row = NTF)
#define NSENT 2554   // invalid (dst,src) slots per batch needing the zero-sentinel
#define ETILES 508   // ceil(P/256) edge tiles per batch

__device__ __forceinline__ float dot3(float ax, float ay, float az,
                                      float bx, float by, float bz) {
    return fmaf(ax, bx, fmaf(ay, by, az * bz));
}

__device__ __forceinline__ uint16_t bf16_bits(float f) {
    union { __hip_bfloat16 h; uint16_t u; } cv;
    cv.h = __float2bfloat16(f);
    return cv.u;
}

// writhe scalar for edge (i,j), i<j — verified (R2..R14 absmax 0.0625).
// pb may point to LDS (generic pointer) — xyz layout [atom][3].
__device__ __forceinline__ float compute_wr(const float* pb, int i, int j) {
    float p0x = pb[3*i+0], p0y = pb[3*i+1], p0z = pb[3*i+2];
    float p1x = pb[3*i+3], p1y = pb[3*i+4], p1z = pb[3*i+5];
    float p2x = pb[3*j+0], p2y = pb[3*j+1], p2z = pb[3*j+2];
    float p3x = pb[3*j+3], p3y = pb[3*j+4], p3z = pb[3*j+5];

    float d0x = p2x-p0x, d0y = p2y-p0y, d0z = p2z-p0z;
    float d1x = p3x-p0x, d1y = p3y-p0y, d1z = p3z-p0z;
    float d2x = p2x-p1x, d2y = p2y-p1y, d2z = p2z-p1z;
    float d3x = p3x-p1x, d3y = p3y-p1y, d3z = p3z-p1z;
    {
        float n0 = rsqrtf(dot3(d0x,d0y,d0z,d0x,d0y,d0z)); d0x*=n0; d0y*=n0; d0z*=n0;
        float n1 = rsqrtf(dot3(d1x,d1y,d1z,d1x,d1y,d1z)); d1x*=n1; d1y*=n1; d1z*=n1;
        float n2 = rsqrtf(dot3(d2x,d2y,d2z,d2x,d2y,d2z)); d2x*=n2; d2y*=n2; d2z*=n2;
        float n3 = rsqrtf(dot3(d3x,d3y,d3z,d3x,d3y,d3z)); d3x*=n3; d3y*=n3; d3z*=n3;
    }
    float c0x = d0y*d1z - d0z*d1y, c0y = d0z*d1x - d0x*d1z, c0z = d0x*d1y - d0y*d1x;
    float c1x = d1y*d3z - d1z*d3y, c1y = d1z*d3x - d1x*d3z, c1z = d1x*d3y - d1y*d3x;
    float c3x = d2y*d0z - d2z*d0y, c3y = d2z*d0x - d2x*d0z, c3z = d2x*d0y - d2y*d0x;
    {
        float n0 = rsqrtf(dot3(c0x,c0y,c0z,c0x,c0y,c0z)); c0x*=n0; c0y*=n0; c0z*=n0;
        float n1 = rsqrtf(dot3(c1x,c1y,c1z,c1x,c1y,c1z)); c1x*=n1; c1y*=n1; c1z*=n1;
        float n3 = rsqrtf(dot3(c3x,c3y,c3z,c3x,c3y,c3z)); c3x*=n3; c3y*=n3; c3z*=n3;
    }
    float t0 = fminf(fmaxf(dot3(c0x,c0y,c0z, c1x,c1y,c1z), -1.f), 1.f);
    float t1 = fminf(fmaxf(dot3(c1x,c1y,c1z, c3x,c3y,c3z), -1.f), 1.f);
    float t3 = fminf(fmaxf(dot3(c3x,c3y,c3z, c0x,c0y,c0z), -1.f), 1.f);
    float omega = asinf(t0) + asinf(t1) + asinf(t3) + 1.5707963267948966f;
    float ex = p3x-p2x, ey = p3y-p2y, ez = p3z-p2z;
    float fx = p1x-p0x, fy = p1y-p0y, fz = p1z-p0z;
    float gx = ey*fz - ez*fy, gy = ez*fx - ex*fz, gz = ex*fy - ey*fx;
    float sgd = dot3(gx,gy,gz, d0x,d0y,d0z);
    float sgn = (sgd > 0.f) ? 1.f : ((sgd < 0.f) ? -1.f : 0.f);
    return omega * sgn * 0.15915494309189535f;
}

// ---------------- launch 1: mega-prepass ----------------------------------------
// block ranges: [0,2048) table build | [2048, +4064) edge writhes (xyz in LDS)
//               | next 1024 out=x copy | next 80 sentinel fill.
__launch_bounds__(256)
__global__ void prepass(
        const float* __restrict__ xyz, const int* __restrict__ seg,
        const float* __restrict__ x, float* __restrict__ out,
        const float* __restrict__ W1, const float* __restrict__ b1,
        const float* __restrict__ W2, const float* __restrict__ b2,
        uint16_t* __restrict__ tabh, uint32_t* __restrict__ ta, int P) {
    __shared__ float lds[1536];   // build: lh[4][64] uses first 256; edge: xyz[b]

    const unsigned bx = blockIdx.x;

    if (bx < NTF / 4) {
        // ---------------- bf16 fine-table build (exact fp32 MLP, ILP-4) ---------
        const int widx = threadIdx.x >> 6;
        const int lane = threadIdx.x & 63;
        const int g = bx * 4 + widx;

        float wr = -1.0f + (2.0f / (float)(NTF - 1)) * (float)g;
        float tt = (wr + 1.0f) * 31.5f;   // rbf mapping proven R2..R14

        float h0 = 0.f, h1 = 0.f, h2 = 0.f, h3 = 0.f;
        #pragma unroll
        for (int k = 0; k < NBINS; k += 4) {
            float d0 = tt - (float)(k + 0);
            float d1 = tt - (float)(k + 1);
            float d2 = tt - (float)(k + 2);
            float d3 = tt - (float)(k + 3);
            h0 = fmaf(__expf(-d0 * d0) * 0.8928571428571429f, W1[(k + 0) * NF + lane], h0);
            h1 = fmaf(__expf(-d1 * d1) * 0.8928571428571429f, W1[(k + 1) * NF + lane], h1);
            h2 = fmaf(__expf(-d2 * d2) * 0.8928571428571429f, W1[(k + 2) * NF + lane], h2);
            h3 = fmaf(__expf(-d3 * d3) * 0.8928571428571429f, W1[(k + 3) * NF + lane], h3);
        }
        float h = ((h0 + h1) + (h2 + h3)) + b1[lane];
        h = fmaxf(h, 0.01f * h);
        lds[widx * 64 + lane] = h;
        __syncthreads();

        float m0 = 0.f, m1 = 0.f, m2 = 0.f, m3 = 0.f;
        #pragma unroll
        for (int k = 0; k < NF; k += 4) {
            m0 = fmaf(lds[widx * 64 + k + 0], W2[(k + 0) * NF + lane], m0);
            m1 = fmaf(lds[widx * 64 + k + 1], W2[(k + 1) * NF + lane], m1);
            m2 = fmaf(lds[widx * 64 + k + 2], W2[(k + 2) * NF + lane], m2);
            m3 = fmaf(lds[widx * 64 + k + 3], W2[(k + 3) * NF + lane], m3);
        }
        float m = ((m0 + m1) + (m2 + m3)) + b2[lane];
        tabh[g * NF + lane] = bf16_bits(m);
        if (g == 0) tabh[NTF * NF + lane] = 0;     // sentinel zero row
    } else if (bx < NTF / 4 + NB * ETILES) {
        // ---------------- edge writhes, xyz[b] staged in LDS --------------------
        const int rel = bx - NTF / 4;
        const int b = rel / ETILES;
        const int tile = rel - b * ETILES;

        const float* xb = xyz + b * (N_ATOMS * 3);
        #pragma unroll
        for (int k = 0; k < 6; ++k)
            lds[k * 256 + threadIdx.x] = xb[k * 256 + threadIdx.x];
        __syncthreads();

        const int e = tile * 256 + threadIdx.x;
        if (e < P) {
            int4 sv = ((const int4*)seg)[e];
            const int i = sv.x;
            const int j = sv.z;

            float w  = compute_wr(lds, i, j);            // LDS reads (~5 cyc)
            float tf = (w + 1.0f) * ((float)(NTF - 1) * 0.5f);
            tf = fminf(fmaxf(tf, 0.0f), (float)(NTF - 1));
            int t0 = (int)(tf + 0.5f);                   // nearest
            t0 = (t0 > NTF - 1) ? (NTF - 1) : t0;
            uint32_t u = (uint32_t)t0 << 6;              // pre-shifted elem offset

            ta[(b << 18) + (i << 9) + j] = u;
            ta[(b << 18) + (j << 9) + i] = u;            // mirror (m symmetric)
        }
    } else if (bx < NTF / 4 + NB * ETILES + 1024) {
        // ---------------- out = x copy ------------------------------------------
        const int tid = (bx - (NTF / 4 + NB * ETILES)) * 256 + threadIdx.x;
        out[tid] = x[tid];
    } else {
        // ---------------- sentinel fill -----------------------------------------
        const int idx = (bx - (NTF / 4 + NB * ETILES + 1024)) * 256 + threadIdx.x;
        if (idx < NB * NSENT) {
            const int b = idx / NSENT;
            const int k = idx - b * NSENT;
            int d, s;
            if      (k < 512)  { d = k;        s = k;     }   // diagonal
            else if (k < 1023) { d = k - 512;  s = d + 1; }   // upper band
            else if (k < 1534) { s = k - 1023; d = s + 1; }   // lower band
            else if (k < 2044) { d = k - 1534; s = NSEG;  }   // col 511 (d<=509)
            else               { s = k - 2044; d = NSEG;  }   // row 511 (s<=509)
            ta[(b << 18) + (d << 9) + s] = (uint32_t)NTF << 6;  // -> zero row
        }
    }
}

// ---------------- launch 2: aggregation — 8-wave x-share + bf16 table -----------
// Block = 8 waves (512 thr) sharing (b, chunk c); dst = dgrp*8 + widx. x-chunk
// (16 KB) staged once per block -> 67 MB total x L2 traffic (÷2 vs R14). Inner
// iter: readlane(const) -> SGPR row offset; bf16 tab load; LDS x read; fma.
// Invalid srcs hit the zero sentinel row -> contribute exactly 0.
__launch_bounds__(512)
__global__ void agg9(
        const float* __restrict__ x, const uint32_t* __restrict__ ta,
        const uint16_t* __restrict__ tabh, float* __restrict__ out) {
    __shared__ float lds_x[4096];   // x[b][c*64 .. c*64+63][0..63]

    const int widx = threadIdx.x >> 6;              // 0..7
    const int lane = threadIdx.x & 63;
    const int bid = blockIdx.x;                     // 0..4095
    const int c    = bid & 7;
    const int dgrp = (bid >> 3) & 63;
    const int b    = bid >> 9;
    const int dst  = dgrp * 8 + widx;

    // ---- cooperative x-chunk staging (coalesced, 8 floats/thread) ----
    const float* xc = x + ((size_t)b << 15) + (c << 12);
    #pragma unroll
    for (int k = 0; k < 8; ++k)
        lds_x[k * 512 + threadIdx.x] = xc[k * 512 + threadIdx.x];
    __syncthreads();

    if (dst < NSEG) {
        // per-lane (src = c*64+lane) table row offset — one coalesced 256B load
        const int tav = (int)ta[((size_t)b << 18) + (dst << 9) + (c << 6) + lane];

        float acc = 0.0f;
        #pragma unroll
        for (int ee = 0; ee < 64; ++ee) {
            const int off = __builtin_amdgcn_readlane(tav, ee);   // SGPR elem offset
            const float mv = __uint_as_float((uint32_t)tabh[off + lane] << 16);
            acc = fmaf(mv, lds_x[(ee << 6) + lane], acc);
        }
        atomicAdd(&out[((size_t)b << 15) + (dst << 6) + lane], acc);
    }
}

// ---------------- fallback path (ws too small): R2 atomic kernel (proven) -------

__global__ void init_out_kernel(const float* __restrict__ x, float* __restrict__ out, int n) {
    int idx = blockIdx.x * blockDim.x + threadIdx.x;
    if (idx < n) out[idx] = x[idx];
}

__device__ __forceinline__ void compute_m(
        const float* __restrict__ pb, int i, int j,
        const float* __restrict__ W1, const float* __restrict__ b1,
        const float* __restrict__ W2, const float* __restrict__ b2,
        float* __restrict__ mout) {
    float wr = compute_wr(pb, i, j);
    float acc_[NBINS];
    {
        float tt = (wr + 1.0f) * 31.5f;
        #pragma unroll
        for (int k = 0; k < NBINS; ++k) {
            float d = tt - (float)k;
            acc_[k] = __expf(-d * d) * 0.8928571428571429f;
        }
    }
    float h_[NF];
    #pragma unroll
    for (int f = 0; f < NF; ++f) h_[f] = b1[f];
    #pragma unroll
    for (int k = 0; k < NBINS; ++k) {
        float r = acc_[k];
        #pragma unroll
        for (int f = 0; f < NF; ++f) h_[f] = fmaf(r, W1[k * NF + f], h_[f]);
    }
    #pragma unroll
    for (int f = 0; f < NF; ++f) h_[f] = fmaxf(h_[f], 0.01f * h_[f]);
    #pragma unroll
    for (int f = 0; f < NF; ++f) acc_[f] = b2[f];
    #pragma unroll
    for (int k = 0; k < NF; ++k) {
        float hk = h_[k];
        #pragma unroll
        for (int f = 0; f < NF; ++f) acc_[f] = fmaf(hk, W2[k * NF + f], acc_[f]);
    }
    #pragma unroll
    for (int f = 0; f < NF; ++f) mout[f] = acc_[f];
}

__launch_bounds__(256, 2)
__global__ void writhe_msg_atomic_kernel(
        const float* __restrict__ x, const float* __restrict__ xyz,
        const int* __restrict__ seg,
        const float* __restrict__ W1, const float* __restrict__ b1,
        const float* __restrict__ W2, const float* __restrict__ b2,
        float* __restrict__ out, int P, int n_tiles) {
    __shared__ __hip_bfloat16 lds_m[4][64 * 65];
    __shared__ int lds_i[4][64];
    __shared__ int lds_j[4][64];

    const int widx = threadIdx.x >> 6;
    const int lane = threadIdx.x & 63;
    const int wave_g = blockIdx.x * 4 + widx;
    const int b = wave_g / n_tiles;
    const int tile = wave_g - b * n_tiles;
    const int bc = (b < NB) ? b : 0;
    const int e = tile * 64 + lane;
    const bool valid = (b < NB) && (e < P);

    int4 sv = valid ? ((const int4*)seg)[e] : make_int4(0, 1, 2, 3);
    const int i = sv.x;
    const int j = sv.z;

    float m[NF];
    compute_m(xyz + bc * (N_ATOMS * 3), i, j, W1, b1, W2, b2, m);

    const float scale = valid ? 1.0f : 0.0f;
    #pragma unroll
    for (int f = 0; f < NF; ++f)
        lds_m[widx][lane * 65 + f] = __float2bfloat16(m[f] * scale);
    lds_i[widx][lane] = i;
    lds_j[widx][lane] = j;
    __syncthreads();

    const float* xb = x + bc * (N_ATOMS * NF);
    float* ob = out + bc * (N_ATOMS * NF);
    int cur_i = lds_i[widx][0];
    float acc_i = 0.0f;
    for (int ee = 0; ee < 64; ++ee) {
        int ie = lds_i[widx][ee];
        int je = lds_j[widx][ee];
        float mv = __bfloat162float(lds_m[widx][ee * 65 + lane]);
        float xi = xb[ie * NF + lane];
        float xj = xb[je * NF + lane];
        atomicAdd(&ob[je * NF + lane], mv * xi);
        if (ie != cur_i) {
            atomicAdd(&ob[cur_i * NF + lane], acc_i);
            acc_i = 0.0f;
            cur_i = ie;
        }
        acc_i = fmaf(mv, xj, acc_i);
    }
    atomicAdd(&ob[cur_i * NF + lane], acc_i);
}

extern "C" void kernel_launch(void* const* d_in, const int* in_sizes, int n_in,
                              void* d_out, int out_size, void* d_ws, size_t ws_size,
                              hipStream_t stream) {
    const float* x   = (const float*)d_in[0];
    const float* xyz = (const float*)d_in[1];
    const int*   seg = (const int*)d_in[2];
    const float* W1  = (const float*)d_in[3];
    const float* b1  = (const float*)d_in[4];
    const float* W2  = (const float*)d_in[5];
    const float* b2  = (const float*)d_in[6];
    float* out = (float*)d_out;

    const int P = in_sizes[2] / 4;              // 129795 edges
    const int n_tiles = (P + 63) / 64;          // 2029

    const size_t tabh_bytes = (size_t)(NTF + 1) * NF * sizeof(uint16_t);         // 1.05 MB
    const size_t ta_bytes   = (size_t)NB * N_ATOMS * N_ATOMS * sizeof(uint32_t); // 8 MB
    const size_t need_ws = tabh_bytes + ta_bytes;

    if (ws_size >= need_ws && P <= ETILES * 256) {
        uint16_t* tabh = (uint16_t*)d_ws;
        uint32_t* ta   = (uint32_t*)((char*)d_ws + tabh_bytes);

        const int nsent_blocks = (NB * NSENT + 255) / 256;            // 80
        const int total_blocks = NTF / 4 + NB * ETILES + 1024 + nsent_blocks;
        hipLaunchKernelGGL(prepass, dim3(total_blocks), dim3(256), 0, stream,
                           xyz, seg, x, out, W1, b1, W2, b2, tabh, ta, P);

        hipLaunchKernelGGL(agg9, dim3(NB * 64 * 8), dim3(512), 0, stream,
                           x, ta, tabh, out);
    } else {
        const int n = out_size;
        hipLaunchKernelGGL(init_out_kernel, dim3((n + 255) / 256), dim3(256), 0, stream,
                           x, out, n);
        const int total_waves = NB * n_tiles;
        const int blocks = (total_waves + 3) / 4;
        hipLaunchKernelGGL(writhe_msg_atomic_kernel, dim3(blocks), dim3(256), 0, stream,
                           x, xyz, seg, W1, b1, W2, b2, out, P, n_tiles);
    }
}

// Round 16
// 110.717 us; speedup vs baseline: 1.6488x; 1.0021x over previous
//
#include <hip/hip_runtime.h>
#include <hip/hip_bf16.h>
#include <math.h>
#include <stdint.h>

#define N_ATOMS 512
#define NF 64
#define NB 8
#define NBINS 64
#define NSEG 511     // segment nodes 0..510; valid pairs i<j, j>=i+2
#define NTF 8192     // fine m(wr) grid (nearest; bf16; sentinel row = NTF)
#define NSENT 2554   // invalid (dst,src) slots per batch needing the zero-sentinel
#define ETILES2 254  // ceil(P/512) edge tiles per batch (2 edges/thread)

__device__ __forceinline__ float dot3(float ax, float ay, float az,
                                      float bx, float by, float bz) {
    return fmaf(ax, bx, fmaf(ay, by, az * bz));
}

__device__ __forceinline__ uint16_t bf16_bits(float f) {
    union { __hip_bfloat16 h; uint16_t u; } cv;
    cv.h = __float2bfloat16(f);
    return cv.u;
}

// writhe scalar for edge (i,j), i<j — verified (R2..R15 absmax 0.0625).
// pb may point to LDS (generic pointer) — xyz layout [atom][3].
__device__ __forceinline__ float compute_wr(const float* pb, int i, int j) {
    float p0x = pb[3*i+0], p0y = pb[3*i+1], p0z = pb[3*i+2];
    float p1x = pb[3*i+3], p1y = pb[3*i+4], p1z = pb[3*i+5];
    float p2x = pb[3*j+0], p2y = pb[3*j+1], p2z = pb[3*j+2];
    float p3x = pb[3*j+3], p3y = pb[3*j+4], p3z = pb[3*j+5];

    float d0x = p2x-p0x, d0y = p2y-p0y, d0z = p2z-p0z;
    float d1x = p3x-p0x, d1y = p3y-p0y, d1z = p3z-p0z;
    float d2x = p2x-p1x, d2y = p2y-p1y, d2z = p2z-p1z;
    float d3x = p3x-p1x, d3y = p3y-p1y, d3z = p3z-p1z;
    {
        float n0 = rsqrtf(dot3(d0x,d0y,d0z,d0x,d0y,d0z)); d0x*=n0; d0y*=n0; d0z*=n0;
        float n1 = rsqrtf(dot3(d1x,d1y,d1z,d1x,d1y,d1z)); d1x*=n1; d1y*=n1; d1z*=n1;
        float n2 = rsqrtf(dot3(d2x,d2y,d2z,d2x,d2y,d2z)); d2x*=n2; d2y*=n2; d2z*=n2;
        float n3 = rsqrtf(dot3(d3x,d3y,d3z,d3x,d3y,d3z)); d3x*=n3; d3y*=n3; d3z*=n3;
    }
    float c0x = d0y*d1z - d0z*d1y, c0y = d0z*d1x - d0x*d1z, c0z = d0x*d1y - d0y*d1x;
    float c1x = d1y*d3z - d1z*d3y, c1y = d1z*d3x - d1x*d3z, c1z = d1x*d3y - d1y*d3x;
    float c3x = d2y*d0z - d2z*d0y, c3y = d2z*d0x - d2x*d0z, c3z = d2x*d0y - d2y*d0x;
    {
        float n0 = rsqrtf(dot3(c0x,c0y,c0z,c0x,c0y,c0z)); c0x*=n0; c0y*=n0; c0z*=n0;
        float n1 = rsqrtf(dot3(c1x,c1y,c1z,c1x,c1y,c1z)); c1x*=n1; c1y*=n1; c1z*=n1;
        float n3 = rsqrtf(dot3(c3x,c3y,c3z,c3x,c3y,c3z)); c3x*=n3; c3y*=n3; c3z*=n3;
    }
    float t0 = fminf(fmaxf(dot3(c0x,c0y,c0z, c1x,c1y,c1z), -1.f), 1.f);
    float t1 = fminf(fmaxf(dot3(c1x,c1y,c1z, c3x,c3y,c3z), -1.f), 1.f);
    float t3 = fminf(fmaxf(dot3(c3x,c3y,c3z, c0x,c0y,c0z), -1.f), 1.f);
    float omega = asinf(t0) + asinf(t1) + asinf(t3) + 1.5707963267948966f;
    float ex = p3x-p2x, ey = p3y-p2y, ez = p3z-p2z;
    float fx = p1x-p0x, fy = p1y-p0y, fz = p1z-p0z;
    float gx = ey*fz - ez*fy, gy = ez*fx - ex*fz, gz = ex*fy - ey*fx;
    float sgd = dot3(gx,gy,gz, d0x,d0y,d0z);
    float sgn = (sgd > 0.f) ? 1.f : ((sgd < 0.f) ? -1.f : 0.f);
    return omega * sgn * 0.15915494309189535f;
}

// map wr -> pre-shifted nearest table element offset (proven R13..R15)
__device__ __forceinline__ uint32_t wr_to_off(float w) {
    float tf = (w + 1.0f) * ((float)(NTF - 1) * 0.5f);
    tf = fminf(fmaxf(tf, 0.0f), (float)(NTF - 1));
    int t0 = (int)(tf + 0.5f);
    t0 = (t0 > NTF - 1) ? (NTF - 1) : t0;
    return (uint32_t)t0 << 6;
}

// ---------------- launch 1: mega-prepass ----------------------------------------
// block ranges: [0,1024) table build (2 pts/wave) | [+2032) edge writhes
//   (xyz in LDS, 2 edges/thread) | next 1024 out=x copy | next 80 sentinel fill.
__launch_bounds__(256)
__global__ void prepass(
        const float* __restrict__ xyz, const int* __restrict__ seg,
        const float* __restrict__ x, float* __restrict__ out,
        const float* __restrict__ W1, const float* __restrict__ b1,
        const float* __restrict__ W2, const float* __restrict__ b2,
        uint16_t* __restrict__ tabh, uint32_t* __restrict__ ta, int P) {
    __shared__ float lds[1536];   // build: 2x lh[4][64]; edge: xyz[b] (6 KB)

    const unsigned bx = blockIdx.x;

    if (bx < NTF / 8) {
        // ------- bf16 fine-table build: wave handles g and g+NTF/2 (ILP x2) -----
        const int widx = threadIdx.x >> 6;
        const int lane = threadIdx.x & 63;
        const int g = bx * 4 + widx;              // 0..4095
        const int g2 = g + NTF / 2;               // 4096..8191

        float tta = ((-1.0f + (2.0f / (float)(NTF - 1)) * (float)g)  + 1.0f) * 31.5f;
        float ttb = ((-1.0f + (2.0f / (float)(NTF - 1)) * (float)g2) + 1.0f) * 31.5f;

        float a0=0.f,a1=0.f,a2=0.f,a3=0.f, e0=0.f,e1=0.f,e2=0.f,e3=0.f;
        #pragma unroll
        for (int k = 0; k < NBINS; k += 4) {
            #pragma unroll
            for (int q = 0; q < 4; ++q) {
                float da = tta - (float)(k + q);
                float db = ttb - (float)(k + q);
                float ra = __expf(-da * da) * 0.8928571428571429f;
                float rb = __expf(-db * db) * 0.8928571428571429f;
                float wv = W1[(k + q) * NF + lane];
                if (q == 0) { a0 = fmaf(ra, wv, a0); e0 = fmaf(rb, wv, e0); }
                if (q == 1) { a1 = fmaf(ra, wv, a1); e1 = fmaf(rb, wv, e1); }
                if (q == 2) { a2 = fmaf(ra, wv, a2); e2 = fmaf(rb, wv, e2); }
                if (q == 3) { a3 = fmaf(ra, wv, a3); e3 = fmaf(rb, wv, e3); }
            }
        }
        float ha = ((a0 + a1) + (a2 + a3)) + b1[lane];
        float hb = ((e0 + e1) + (e2 + e3)) + b1[lane];
        ha = fmaxf(ha, 0.01f * ha);
        hb = fmaxf(hb, 0.01f * hb);
        lds[widx * 64 + lane]       = ha;
        lds[256 + widx * 64 + lane] = hb;
        __syncthreads();

        float m0=0.f,m1=0.f,m2=0.f,m3=0.f, n0=0.f,n1=0.f,n2=0.f,n3=0.f;
        #pragma unroll
        for (int k = 0; k < NF; k += 4) {
            float w0 = W2[(k + 0) * NF + lane];
            float w1v = W2[(k + 1) * NF + lane];
            float w2v = W2[(k + 2) * NF + lane];
            float w3 = W2[(k + 3) * NF + lane];
            m0 = fmaf(lds[widx * 64 + k + 0], w0, m0);
            m1 = fmaf(lds[widx * 64 + k + 1], w1v, m1);
            m2 = fmaf(lds[widx * 64 + k + 2], w2v, m2);
            m3 = fmaf(lds[widx * 64 + k + 3], w3, m3);
            n0 = fmaf(lds[256 + widx * 64 + k + 0], w0, n0);
            n1 = fmaf(lds[256 + widx * 64 + k + 1], w1v, n1);
            n2 = fmaf(lds[256 + widx * 64 + k + 2], w2v, n2);
            n3 = fmaf(lds[256 + widx * 64 + k + 3], w3, n3);
        }
        float ma = ((m0 + m1) + (m2 + m3)) + b2[lane];
        float mb = ((n0 + n1) + (n2 + n3)) + b2[lane];
        tabh[g  * NF + lane] = bf16_bits(ma);
        tabh[g2 * NF + lane] = bf16_bits(mb);
        if (g == 0) tabh[NTF * NF + lane] = 0;     // sentinel zero row
    } else if (bx < NTF / 8 + NB * ETILES2) {
        // ------- edge writhes, xyz[b] in LDS, 2 independent edges/thread --------
        const int rel = bx - NTF / 8;
        const int b = rel / ETILES2;
        const int tile = rel - b * ETILES2;

        const float* xb = xyz + b * (N_ATOMS * 3);
        #pragma unroll
        for (int k = 0; k < 6; ++k)
            lds[k * 256 + threadIdx.x] = xb[k * 256 + threadIdx.x];
        __syncthreads();

        #pragma unroll
        for (int q = 0; q < 2; ++q) {
            const int e = tile * 512 + q * 256 + threadIdx.x;
            if (e < P) {
                int4 sv = ((const int4*)seg)[e];
                const int i = sv.x;
                const int j = sv.z;
                uint32_t u = wr_to_off(compute_wr(lds, i, j));
                ta[(b << 18) + (i << 9) + j] = u;
                ta[(b << 18) + (j << 9) + i] = u;   // mirror (m symmetric)
            }
        }
    } else if (bx < NTF / 8 + NB * ETILES2 + 1024) {
        // ------- out = x copy ---------------------------------------------------
        const int tid = (bx - (NTF / 8 + NB * ETILES2)) * 256 + threadIdx.x;
        out[tid] = x[tid];
    } else {
        // ------- sentinel fill --------------------------------------------------
        const int idx = (bx - (NTF / 8 + NB * ETILES2 + 1024)) * 256 + threadIdx.x;
        if (idx < NB * NSENT) {
            const int b = idx / NSENT;
            const int k = idx - b * NSENT;
            int d, s;
            if      (k < 512)  { d = k;        s = k;     }   // diagonal
            else if (k < 1023) { d = k - 512;  s = d + 1; }   // upper band
            else if (k < 1534) { s = k - 1023; d = s + 1; }   // lower band
            else if (k < 2044) { d = k - 1534; s = NSEG;  }   // col 511 (d<=509)
            else               { s = k - 2044; d = NSEG;  }   // row 511 (s<=509)
            ta[(b << 18) + (d << 9) + s] = (uint32_t)NTF << 6;  // -> zero row
        }
    }
}

// ---------------- launch 2: aggregation — 16-wave x-share + bf16 table ----------
// Block = 16 waves (1024 thr) sharing (b, chunk c); dst = dgrp*16 + widx.
// x-chunk (16 KB) staged once -> 34 MB total x L2 traffic. Inner iter (proven
// R13..R15): readlane(const) -> SGPR elem offset; bf16 tab load; LDS x; fma.
__launch_bounds__(1024)
__global__ void agg10(
        const float* __restrict__ x, const uint32_t* __restrict__ ta,
        const uint16_t* __restrict__ tabh, float* __restrict__ out) {
    __shared__ float lds_x[4096];   // x[b][c*64 .. c*64+63][0..63]

    const int widx = threadIdx.x >> 6;              // 0..15
    const int lane = threadIdx.x & 63;
    const int bid = blockIdx.x;                     // 0..2047
    const int c    = bid & 7;
    const int dgrp = (bid >> 3) & 31;
    const int b    = bid >> 8;
    const int dst  = dgrp * 16 + widx;

    // ---- cooperative x-chunk staging (coalesced, 4 floats/thread) ----
    const float* xc = x + ((size_t)b << 15) + (c << 12);
    #pragma unroll
    for (int k = 0; k < 4; ++k)
        lds_x[k * 1024 + threadIdx.x] = xc[k * 1024 + threadIdx.x];
    __syncthreads();

    if (dst < NSEG) {
        // per-lane (src = c*64+lane) table element offset — one coalesced load
        const int tav = (int)ta[((size_t)b << 18) + (dst << 9) + (c << 6) + lane];

        float acc = 0.0f;
        #pragma unroll
        for (int ee = 0; ee < 64; ++ee) {
            const int off = __builtin_amdgcn_readlane(tav, ee);   // SGPR elem offset
            const float mv = __uint_as_float((uint32_t)tabh[off + lane] << 16);
            acc = fmaf(mv, lds_x[(ee << 6) + lane], acc);
        }
        atomicAdd(&out[((size_t)b << 15) + (dst << 6) + lane], acc);
    }
}

// ---------------- fallback path (ws too small): R2 atomic kernel (proven) -------

__global__ void init_out_kernel(const float* __restrict__ x, float* __restrict__ out, int n) {
    int idx = blockIdx.x * blockDim.x + threadIdx.x;
    if (idx < n) out[idx] = x[idx];
}

__device__ __forceinline__ void compute_m(
        const float* __restrict__ pb, int i, int j,
        const float* __restrict__ W1, const float* __restrict__ b1,
        const float* __restrict__ W2, const float* __restrict__ b2,
        float* __restrict__ mout) {
    float wr = compute_wr(pb, i, j);
    float acc_[NBINS];
    {
        float tt = (wr + 1.0f) * 31.5f;
        #pragma unroll
        for (int k = 0; k < NBINS; ++k) {
            float d = tt - (float)k;
            acc_[k] = __expf(-d * d) * 0.8928571428571429f;
        }
    }
    float h_[NF];
    #pragma unroll
    for (int f = 0; f < NF; ++f) h_[f] = b1[f];
    #pragma unroll
    for (int k = 0; k < NBINS; ++k) {
        float r = acc_[k];
        #pragma unroll
        for (int f = 0; f < NF; ++f) h_[f] = fmaf(r, W1[k * NF + f], h_[f]);
    }
    #pragma unroll
    for (int f = 0; f < NF; ++f) h_[f] = fmaxf(h_[f], 0.01f * h_[f]);
    #pragma unroll
    for (int f = 0; f < NF; ++f) acc_[f] = b2[f];
    #pragma unroll
    for (int k = 0; k < NF; ++k) {
        float hk = h_[k];
        #pragma unroll
        for (int f = 0; f < NF; ++f) acc_[f] = fmaf(hk, W2[k * NF + f], acc_[f]);
    }
    #pragma unroll
    for (int f = 0; f < NF; ++f) mout[f] = acc_[f];
}

__launch_bounds__(256, 2)
__global__ void writhe_msg_atomic_kernel(
        const float* __restrict__ x, const float* __restrict__ xyz,
        const int* __restrict__ seg,
        const float* __restrict__ W1, const float* __restrict__ b1,
        const float* __restrict__ W2, const float* __restrict__ b2,
        float* __restrict__ out, int P, int n_tiles) {
    __shared__ __hip_bfloat16 lds_m[4][64 * 65];
    __shared__ int lds_i[4][64];
    __shared__ int lds_j[4][64];

    const int widx = threadIdx.x >> 6;
    const int lane = threadIdx.x & 63;
    const int wave_g = blockIdx.x * 4 + widx;
    const int b = wave_g / n_tiles;
    const int tile = wave_g - b * n_tiles;
    const int bc = (b < NB) ? b : 0;
    const int e = tile * 64 + lane;
    const bool valid = (b < NB) && (e < P);

    int4 sv = valid ? ((const int4*)seg)[e] : make_int4(0, 1, 2, 3);
    const int i = sv.x;
    const int j = sv.z;

    float m[NF];
    compute_m(xyz + bc * (N_ATOMS * 3), i, j, W1, b1, W2, b2, m);

    const float scale = valid ? 1.0f : 0.0f;
    #pragma unroll
    for (int f = 0; f < NF; ++f)
        lds_m[widx][lane * 65 + f] = __float2bfloat16(m[f] * scale);
    lds_i[widx][lane] = i;
    lds_j[widx][lane] = j;
    __syncthreads();

    const float* xb = x + bc * (N_ATOMS * NF);
    float* ob = out + bc * (N_ATOMS * NF);
    int cur_i = lds_i[widx][0];
    float acc_i = 0.0f;
    for (int ee = 0; ee < 64; ++ee) {
        int ie = lds_i[widx][ee];
        int je = lds_j[widx][ee];
        float mv = __bfloat162float(lds_m[widx][ee * 65 + lane]);
        float xi = xb[ie * NF + lane];
        float xj = xb[je * NF + lane];
        atomicAdd(&ob[je * NF + lane], mv * xi);
        if (ie != cur_i) {
            atomicAdd(&ob[cur_i * NF + lane], acc_i);
            acc_i = 0.0f;
            cur_i = ie;
        }
        acc_i = fmaf(mv, xj, acc_i);
    }
    atomicAdd(&ob[cur_i * NF + lane], acc_i);
}

extern "C" void kernel_launch(void* const* d_in, const int* in_sizes, int n_in,
                              void* d_out, int out_size, void* d_ws, size_t ws_size,
                              hipStream_t stream) {
    const float* x   = (const float*)d_in[0];
    const float* xyz = (const float*)d_in[1];
    const int*   seg = (const int*)d_in[2];
    const float* W1  = (const float*)d_in[3];
    const float* b1  = (const float*)d_in[4];
    const float* W2  = (const float*)d_in[5];
    const float* b2  = (const float*)d_in[6];
    float* out = (float*)d_out;

    const int P = in_sizes[2] / 4;              // 129795 edges
    const int n_tiles = (P + 63) / 64;          // 2029

    const size_t tabh_bytes = (size_t)(NTF + 1) * NF * sizeof(uint16_t);         // 1.05 MB
    const size_t ta_bytes   = (size_t)NB * N_ATOMS * N_ATOMS * sizeof(uint32_t); // 8 MB
    const size_t need_ws = tabh_bytes + ta_bytes;

    if (ws_size >= need_ws && P <= ETILES2 * 512) {
        uint16_t* tabh = (uint16_t*)d_ws;
        uint32_t* ta   = (uint32_t*)((char*)d_ws + tabh_bytes);

        const int nsent_blocks = (NB * NSENT + 255) / 256;            // 80
        const int total_blocks = NTF / 8 + NB * ETILES2 + 1024 + nsent_blocks;
        hipLaunchKernelGGL(prepass, dim3(total_blocks), dim3(256), 0, stream,
                           xyz, seg, x, out, W1, b1, W2, b2, tabh, ta, P);

        hipLaunchKernelGGL(agg10, dim3(NB * 32 * 8), dim3(1024), 0, stream,
                           x, ta, tabh, out);
    } else {
        const int n = out_size;
        hipLaunchKernelGGL(init_out_kernel, dim3((n + 255) / 256), dim3(256), 0, stream,
                           x, out, n);
        const int total_waves = NB * n_tiles;
        const int blocks = (total_waves + 3) / 4;
        hipLaunchKernelGGL(writhe_msg_atomic_kernel, dim3(blocks), dim3(256), 0, stream,
                           x, xyz, seg, W1, b1, W2, b2, out, P, n_tiles);
    }
}